// Round 15
// baseline (422.769 us; speedup 1.0000x reference)
//
#include <hip/hip_runtime.h>
#include <hip/hip_bf16.h>
#include <hip/hip_fp16.h>
#include <math.h>

#define B_   16
#define C_   16
#define S_   64
#define HW_  4096
#define T_   50
#define K_   26
#define F_   416   // C_*K_
#define HID_ 256
#define NC_  7
#define DT_  0.5f
#define BCHW_ (B_*C_*HW_)
#define M_   (B_*HW_)   // 65536 rows into the MLP

typedef _Float16 f16x8  __attribute__((ext_vector_type(8)));
typedef __fp16   fp16x2 __attribute__((ext_vector_type(2)));
typedef float    f32x4  __attribute__((ext_vector_type(4)));
typedef float    f32x2  __attribute__((ext_vector_type(2)));

__device__ __forceinline__ void gld_lds16(const void* g, void* l){
    __builtin_amdgcn_global_load_lds(
        (const __attribute__((address_space(1))) void*)g,
        (__attribute__((address_space(3))) void*)l, 16, 0, 0);
}

__device__ __forceinline__ float fast_tanh(float x){
    float ax = fabsf(x);
    float e  = __expf(2.f*ax);
    float r  = 1.f - 2.f/(e + 1.f);
    return copysignf(r, x);
}

__device__ __forceinline__ short f2h_s(float f){
    __half h = __float2half(f);
    return *(short*)&h;
}

// ---------------------------------------------------------------------------
// Fused multi-chain 3x3 conv (unchanged from round 12).
// ---------------------------------------------------------------------------
template<int CIN, int ACT>
__global__ __launch_bounds__(256) void convf_kernel(
    const float* __restrict__ in0, const float* __restrict__ in1, const float* __restrict__ in2,
    const float* __restrict__ w0,  const float* __restrict__ w1,  const float* __restrict__ w2,
    const float* __restrict__ b0,  const float* __restrict__ b1,  const float* __restrict__ b2,
    float* __restrict__ o0, float* __restrict__ o1, float* __restrict__ o2)
{
    __shared__ __align__(16) float slab[CIN][10][66];
    const int slice = blockIdx.x;
    const int b     = blockIdx.y;
    const int ch    = blockIdx.z;
    const float* in = (ch == 0) ? in0 : (ch == 1) ? in1 : in2;
    const float* w  = (ch == 0) ? w0  : (ch == 1) ? w1  : w2;
    const float* bb = (ch == 0) ? b0  : (ch == 1) ? b1  : b2;
    float* out      = (ch == 0) ? o0  : (ch == 1) ? o1  : o2;

    const int tid = threadIdx.x;
    const int y0  = slice * 8;

    for (int idx = tid; idx < CIN*10*66; idx += 256){
        int ci  = idx / (10*66);
        int rem = idx % (10*66);
        int rr  = rem / 66;
        int cc  = rem % 66;
        int gy = y0 - 1 + rr;
        int gx = cc - 1;
        float v = 0.f;
        if ((unsigned)gy < 64u && (unsigned)gx < 64u)
            v = in[(size_t)(b*CIN + ci)*HW_ + gy*64 + gx];
        slab[ci][rr][cc] = v;
    }
    __syncthreads();

    const int x2 = (tid & 31) * 2;
    const int ry = tid >> 5;

    f32x2 acc[16];
    #pragma unroll
    for (int co = 0; co < 16; co++) acc[co] = (f32x2){bb[co], bb[co]};

    for (int ci = 0; ci < CIN; ci++){
        f32x2 p[3][3];
        #pragma unroll
        for (int dy = 0; dy < 3; dy++){
            float s0 = slab[ci][ry + dy][x2 + 0];
            float s1 = slab[ci][ry + dy][x2 + 1];
            float s2 = slab[ci][ry + dy][x2 + 2];
            float s3 = slab[ci][ry + dy][x2 + 3];
            p[dy][0] = (f32x2){s0, s1};
            p[dy][1] = (f32x2){s1, s2};
            p[dy][2] = (f32x2){s2, s3};
        }
        #pragma unroll
        for (int co = 0; co < 16; co++){
            const float* wp = w + (size_t)(co*CIN + ci)*9;
            f32x2 s = acc[co];
            #pragma unroll
            for (int dy = 0; dy < 3; dy++)
                #pragma unroll
                for (int dx = 0; dx < 3; dx++){
                    float wc = wp[dy*3 + dx];
                    s += (f32x2){wc, wc} * p[dy][dx];
                }
            acc[co] = s;
        }
    }
    #pragma unroll
    for (int co = 0; co < 16; co++){
        float v0 = acc[co].x, v1 = acc[co].y;
        if (ACT){ v0 = fast_tanh(v0); v1 = fast_tanh(v1); }
        else    { v0 = fmaxf(v0, 0.f); v1 = fmaxf(v1, 0.f); }
        *(float2*)&out[(size_t)(b*16 + co)*HW_ + (y0 + ry)*64 + x2] =
            make_float2(v0, v1);
    }
}

// ---------------------------------------------------------------------------
// 50-step coRNN ODE (unchanged from round 12).
// ---------------------------------------------------------------------------
__global__ __launch_bounds__(1024) void ode_kernel(
    const float* __restrict__ omega, const float* __restrict__ alpha,
    const float* __restrict__ hy0,   const float* __restrict__ wy,
    __half* __restrict__ yseq)
{
    __shared__ __align__(16) float buf[2][64*68];
    const int blk = blockIdx.x;            // b*16 + c
    const int c   = blk & 15;
    const int tid = threadIdx.x;
    const int y   = tid >> 4;
    const int xq  = (tid & 15) << 2;
    const size_t off = (size_t)blk * HW_;
    const int g0  = y*64 + xq;

    float4 om4 = *(const float4*)(omega + off + g0);
    float4 al4 = *(const float4*)(alpha + off + g0);
    float4 h4  = *(const float4*)(hy0   + off + g0);

    f32x2 om2[2] = { (f32x2){DT_*om4.x, DT_*om4.y}, (f32x2){DT_*om4.z, DT_*om4.w} };
    f32x2 al2[2] = { (f32x2){1.f - DT_*al4.x, 1.f - DT_*al4.y},
                     (f32x2){1.f - DT_*al4.z, 1.f - DT_*al4.w} };
    f32x2 hz2[2] = { (f32x2){0.f, 0.f}, (f32x2){0.f, 0.f} };
    float hv[4]  = { h4.x, h4.y, h4.z, h4.w };
    *(float4*)&buf[0][y*68 + xq] = h4;

    float wv[9];
    const float* wp = wy + (size_t)(c*C_ + c)*9;
    #pragma unroll
    for (int j = 0; j < 9; j++) wv[j] = wp[j];
    const bool five = (wv[0]==0.f) & (wv[2]==0.f) & (wv[6]==0.f) & (wv[8]==0.f);
    const f32x2 w1v = (f32x2){wv[1], wv[1]};
    const f32x2 w3v = (f32x2){wv[3], wv[3]};
    const f32x2 w4v = (f32x2){wv[4], wv[4]};
    const f32x2 w5v = (f32x2){wv[5], wv[5]};
    const f32x2 w7v = (f32x2){wv[7], wv[7]};
    const f32x2 dt2 = (f32x2){DT_, DT_};
    __syncthreads();

    const int ym = ((y + 63) & 63) * 68;
    const int yp = ((y + 1)  & 63) * 68;
    const int yo = y * 68;
    const int xm = (xq + 63) & 63;
    const int xp = (xq + 4)  & 63;
    const __half* ybase = yseq + off + g0;

    int cur = 0;
    for (int t = 0; t < T_; t++){
        const float* hp = buf[cur];
        float* hn = buf[cur ^ 1];
        float4 up4 = *(const float4*)&hp[ym + xq];
        float4 dn4 = *(const float4*)&hp[yp + xq];
        float lft = hp[yo + xm];
        float rgt = hp[yo + xp];

        float ny0, ny1, ny2, ny3;
        if (five){
            f32x2 u0 = (f32x2){up4.x, up4.y}, u1 = (f32x2){up4.z, up4.w};
            f32x2 d0 = (f32x2){dn4.x, dn4.y}, d1 = (f32x2){dn4.z, dn4.w};
            f32x2 c0 = (f32x2){hv[0], hv[1]}, c1 = (f32x2){hv[2], hv[3]};
            f32x2 l0 = (f32x2){lft,  hv[0]};
            f32x2 l1 = (f32x2){hv[1], hv[2]};
            f32x2 r1 = (f32x2){hv[3], rgt};

            f32x2 s0 = w4v*c0 + w1v*u0 + w7v*d0 + w3v*l0 + w5v*l1;
            f32x2 s1 = w4v*c1 + w1v*u1 + w7v*d1 + w3v*l1 + w5v*r1;

            f32x2 sf0 = (f32x2){fast_tanh(s0.x), fast_tanh(s0.y)};
            f32x2 sf1 = (f32x2){fast_tanh(s1.x), fast_tanh(s1.y)};

            f32x2 nz0 = al2[0]*hz2[0] - om2[0]*c0 + dt2*sf0;
            f32x2 nz1 = al2[1]*hz2[1] - om2[1]*c1 + dt2*sf1;
            f32x2 nyv0 = dt2*nz0 + c0;
            f32x2 nyv1 = dt2*nz1 + c1;
            hz2[0] = nz0; hz2[1] = nz1;
            ny0 = nyv0.x; ny1 = nyv0.y; ny2 = nyv1.x; ny3 = nyv1.y;
        } else {
            float upv[4] = {up4.x, up4.y, up4.z, up4.w};
            float dnv[4] = {dn4.x, dn4.y, dn4.z, dn4.w};
            float ul = hp[ym + xm], ur = hp[ym + xp];
            float dl = hp[yp + xm], dr = hp[yp + xp];
            float hzl[4] = {hz2[0].x, hz2[0].y, hz2[1].x, hz2[1].y};
            float oml[4] = {om2[0].x, om2[0].y, om2[1].x, om2[1].y};
            float all[4] = {al2[0].x, al2[0].y, al2[1].x, al2[1].y};
            float nyv[4];
            #pragma unroll
            for (int i = 0; i < 4; i++){
                float l  = (i == 0) ? lft : hv[i-1];
                float r  = (i == 3) ? rgt : hv[i+1];
                float uL = (i == 0) ? ul  : upv[i-1];
                float uR = (i == 3) ? ur  : upv[i+1];
                float dL = (i == 0) ? dl  : dnv[i-1];
                float dR = (i == 3) ? dr  : dnv[i+1];
                float s = wv[0]*uL + wv[1]*upv[i] + wv[2]*uR
                        + wv[3]*l  + wv[4]*hv[i]  + wv[5]*r
                        + wv[6]*dL + wv[7]*dnv[i] + wv[8]*dR;
                float sf = fast_tanh(s);
                float nz = fmaf(all[i], hzl[i], fmaf(-oml[i], hv[i], DT_*sf));
                nyv[i] = fmaf(DT_, nz, hv[i]);
                hzl[i] = nz;
            }
            hz2[0] = (f32x2){hzl[0], hzl[1]};
            hz2[1] = (f32x2){hzl[2], hzl[3]};
            ny0 = nyv[0]; ny1 = nyv[1]; ny2 = nyv[2]; ny3 = nyv[3];
        }

        hv[0] = ny0; hv[1] = ny1; hv[2] = ny2; hv[3] = ny3;
        *(float4*)&hn[yo + xq] = make_float4(ny0, ny1, ny2, ny3);

        union { fp16x2 h2[2]; uint2 u; } pk;
        pk.h2[0] = __builtin_amdgcn_cvt_pkrtz(ny0, ny1);
        pk.h2[1] = __builtin_amdgcn_cvt_pkrtz(ny2, ny3);
        *(uint2*)(ybase + (size_t)t*BCHW_) = pk.u;

        __syncthreads();
        cur ^= 1;
    }
}

// ---------------------------------------------------------------------------
// MFMA DFT (unchanged from round 12). fp16 in/out.
// ---------------------------------------------------------------------------
__global__ __launch_bounds__(256) void dft_mfma_kernel(
    const __half* __restrict__ yseq, __half* __restrict__ f)
{
    __shared__ __align__(16) char Ys[8*256*16];
    __shared__ __align__(16) char Gs[8*64*16];
    const int tid = threadIdx.x;
    const int blk = blockIdx.x;
    const int bc  = blk >> 4;
    const int p0  = (blk & 15) << 8;
    const int b   = bc >> 4, c = bc & 15;

    for (int idx = tid; idx < 64*64; idx += 256){
        int r = idx >> 6, t = idx & 63;
        float v = 0.f;
        if (r < 52 && t < 50){
            int k  = r >> 1;
            int ph = (k * t) % 50;
            float ang = (float)ph * (6.2831853071795864f / 50.f);
            v = (r & 1) ? __sinf(ang) : __cosf(ang);
        }
        *(_Float16*)(Gs + ((t >> 3)*64 + r)*16 + (t & 7)*2) = (_Float16)v;
    }

    {
        const __half* src = yseq + (size_t)bc*HW_ + p0 + tid;
        #pragma unroll
        for (int t2 = 0; t2 < 25; t2++){
            unsigned int a = *(const unsigned short*)&src[(size_t)(2*t2)*BCHW_];
            unsigned int d = *(const unsigned short*)&src[(size_t)(2*t2+1)*BCHW_];
            int t8 = t2 >> 2, j = t2 & 3;
            *(unsigned int*)(Ys + (t8*256 + tid)*16 + j*4) = a | (d << 16);
        }
        #pragma unroll
        for (int t2 = 25; t2 < 32; t2++){
            int t8 = t2 >> 2, j = t2 & 3;
            *(unsigned int*)(Ys + (t8*256 + tid)*16 + j*4) = 0u;
        }
    }
    __syncthreads();

    const int lane = tid & 63;
    const int w    = tid >> 6;
    const int n    = lane & 15;
    const int quad = lane >> 4;
    const int mrow = 16*w + n;

    f16x8 a0 = *(const f16x8*)(Gs + ((quad    )*64 + mrow)*16);
    f16x8 a1 = *(const f16x8*)(Gs + ((quad + 4)*64 + mrow)*16);

    const int kb0   = 8*w + 2*quad;
    const bool valid = (kb0 < K_);

    for (int nt = 0; nt < 16; nt++){
        f16x8 b0 = *(const f16x8*)(Ys + ((quad    )*256 + nt*16 + n)*16);
        f16x8 b1 = *(const f16x8*)(Ys + ((quad + 4)*256 + nt*16 + n)*16);
        f32x4 acc = (f32x4){0.f, 0.f, 0.f, 0.f};
        acc = __builtin_amdgcn_mfma_f32_16x16x32_f16(a0, b0, acc, 0, 0, 0);
        acc = __builtin_amdgcn_mfma_f32_16x16x32_f16(a1, b1, acc, 0, 0, 0);
        if (valid){
            float m0 = sqrtf(fmaf(acc[0], acc[0], acc[1]*acc[1]));
            float m1 = sqrtf(fmaf(acc[2], acc[2], acc[3]*acc[3]));
            unsigned int u = ((unsigned int)(unsigned short)f2h_s(m1) << 16)
                           |  (unsigned int)(unsigned short)f2h_s(m0);
            const int row = b*HW_ + p0 + nt*16 + n;
            *(unsigned int*)((char*)(f + (size_t)row*F_ + c*K_) + kb0*2) = u;
        }
    }
}

// ---------------------------------------------------------------------------
// One merged prep kernel: wt1 [256][416], wt2/wt3 [256][256], all fp16.
// ---------------------------------------------------------------------------
__global__ __launch_bounds__(256) void prep_all_kernel(
    const float* __restrict__ w1, const float* __restrict__ w2,
    const float* __restrict__ w3,
    __half* __restrict__ wt1, __half* __restrict__ wt2, __half* __restrict__ wt3)
{
    const int blk = blockIdx.x;
    const int tid = threadIdx.x;
    if (blk < 256){
        const int n = blk;
        for (int k = tid; k < F_; k += 256)
            wt1[(size_t)n*F_ + k] = __float2half(w1[(size_t)k*HID_ + n]);
    } else if (blk < 512){
        const int n = blk - 256;
        for (int k = tid; k < HID_; k += 256)
            wt2[(size_t)n*HID_ + k] = __float2half(w2[(size_t)k*HID_ + n]);
    } else {
        const int n = blk - 512;
        for (int k = tid; k < HID_; k += 256)
            wt3[(size_t)n*HID_ + k] = __float2half(w3[(size_t)k*HID_ + n]);
    }
}

// ---------------------------------------------------------------------------
// FUSED MLP v5: TILE_M=256, 512 threads = 8 waves (4m x 2n). Layer 1 BK=32
// with afn prefetch (round-12-proven, register-safe). Layers 2/3 BK=64 with
// A-frags read from hbuf INSIDE the h-halves (no extra live registers ->
// no spill; barriers 16->8 per layer). hbuf XOR-swizzled 131,072 B; Bs
// unpadded 32,768 B (r14: fewer conflicts than padded); w4 staged into Bs.
// LDS total 163,840 B.
// ---------------------------------------------------------------------------
__global__ __launch_bounds__(512, 2) void mlp_fused_kernel(
    const __half* __restrict__ A,     // fbuf [M][416]
    const __half* __restrict__ Wt1,   // [256][416]
    const __half* __restrict__ Wt2,   // [256][256]
    const __half* __restrict__ Wt3,   // [256][256]
    const float* __restrict__ b1, const float* __restrict__ b2,
    const float* __restrict__ b3,
    const float* __restrict__ w4, const float* __restrict__ b4,
    float* __restrict__ out)
{
    __shared__ __align__(16) short hbuf[256*256];   // 131,072 B (swizzled)
    __shared__ __align__(16) short Bs[8*256*8];     //  32,768 B

    const int tid  = threadIdx.x;
    const int lane = tid & 63;
    const int wave = tid >> 6;
    const int wm   = (wave & 3) * 64;
    const int wn   = (wave >> 2) * 128;
    const int n16  = lane & 15;
    const int quad = lane >> 4;
    const int m0   = blockIdx.x * 256;

    // BK=32 staging ids (2 chunks/thread): id -> (kc = id>>8 in 0..3, nn)
    const int id0 = tid, id1 = tid + 512;
    const int kc0 = id0 >> 8, nn0 = id0 & 255;
    const int kc1 = id1 >> 8, nn1 = id1 & 255;

    f32x4 acc[4][8];
    #pragma unroll
    for (int i = 0; i < 4; i++)
        #pragma unroll
        for (int j = 0; j < 8; j++)
            acc[i][j] = (f32x4){0.f,0.f,0.f,0.f};

    // ---------------- layer 1: BK=32, A from global (prefetched) ----------
    const __half* arow[4];
    #pragma unroll
    for (int i = 0; i < 4; i++)
        arow[i] = A + (size_t)(m0 + wm + i*16 + n16)*F_ + quad*8;

    f16x8 afn[4];
    #pragma unroll
    for (int i = 0; i < 4; i++) afn[i] = *(const f16x8*)(arow[i]);

    for (int k0 = 0; k0 < F_; k0 += 32){
        gld_lds16(Wt1 + (size_t)nn0*F_ + k0 + kc0*8, (char*)Bs + id0*16);
        gld_lds16(Wt1 + (size_t)nn1*F_ + k0 + kc1*8, (char*)Bs + id1*16);
        __syncthreads();
        f16x8 af[4];
        #pragma unroll
        for (int i = 0; i < 4; i++) af[i] = afn[i];
        if (k0 + 32 < F_){
            #pragma unroll
            for (int i = 0; i < 4; i++) afn[i] = *(const f16x8*)(arow[i] + k0 + 32);
        }
        f16x8 bf[8];
        #pragma unroll
        for (int j = 0; j < 8; j++)
            bf[j] = *(const f16x8*)&Bs[(quad*256 + wn + j*16 + n16)*8];
        #pragma unroll
        for (int i = 0; i < 4; i++)
            #pragma unroll
            for (int j = 0; j < 8; j++)
                acc[i][j] = __builtin_amdgcn_mfma_f32_16x16x32_f16(
                                af[i], bf[j], acc[i][j], 0, 0, 0);
        __syncthreads();
    }
    // epilogue layer 1 -> hbuf (swizzled)
    #pragma unroll
    for (int j = 0; j < 8; j++){
        const int col = wn + j*16 + n16;
        const float bv = b1[col];
        #pragma unroll
        for (int i = 0; i < 4; i++){
            const int r0 = wm + i*16 + quad*4;
            #pragma unroll
            for (int r = 0; r < 4; r++){
                const int row = r0 + r;
                hbuf[row*256 + (((col>>3) ^ (row&7))<<3) + (col&7)] =
                    f2h_s(fmaxf(acc[i][j][r] + bv, 0.f));
            }
        }
    }
    __syncthreads();

    // ---------------- layers 2,3: BK=64, A from hbuf (in-loop reads) ------
    const __half* Wts[2] = {Wt2, Wt3};
    const float* bls[2] = {b2, b3};
    for (int L = 0; L < 2; L++){
        const __half* Wt = Wts[L];
        #pragma unroll
        for (int i = 0; i < 4; i++)
            #pragma unroll
            for (int j = 0; j < 8; j++)
                acc[i][j] = (f32x4){0.f,0.f,0.f,0.f};

        for (int k0 = 0; k0 < HID_; k0 += 64){
            #pragma unroll
            for (int s = 0; s < 4; s++){
                int id = tid + 512*s;              // 0..2047
                int kc = id >> 8;                  // 0..7
                int nn = id & 255;
                gld_lds16(Wt + (size_t)nn*HID_ + k0 + kc*8, (char*)Bs + id*16);
            }
            __syncthreads();
            #pragma unroll
            for (int h = 0; h < 2; h++){
                f16x8 af[4];
                #pragma unroll
                for (int i = 0; i < 4; i++){
                    const int row  = wm + i*16 + n16;
                    const int phys = ((k0>>3) + h*4 + quad) ^ (row & 7);
                    af[i] = *(const f16x8*)&hbuf[row*256 + phys*8];
                }
                f16x8 bf[8];
                #pragma unroll
                for (int j = 0; j < 8; j++)
                    bf[j] = *(const f16x8*)&Bs[((h*4 + quad)*256 + wn + j*16 + n16)*8];
                #pragma unroll
                for (int i = 0; i < 4; i++)
                    #pragma unroll
                    for (int j = 0; j < 8; j++)
                        acc[i][j] = __builtin_amdgcn_mfma_f32_16x16x32_f16(
                                        af[i], bf[j], acc[i][j], 0, 0, 0);
            }
            __syncthreads();
        }
        const float* bl = bls[L];
        #pragma unroll
        for (int j = 0; j < 8; j++){
            const int col = wn + j*16 + n16;
            const float bv = bl[col];
            #pragma unroll
            for (int i = 0; i < 4; i++){
                const int r0 = wm + i*16 + quad*4;
                #pragma unroll
                for (int r = 0; r < 4; r++){
                    const int row = r0 + r;
                    hbuf[row*256 + (((col>>3) ^ (row&7))<<3) + (col&7)] =
                        f2h_s(fmaxf(acc[i][j][r] + bv, 0.f));
                }
            }
        }
        __syncthreads();
    }

    // ---------------- final layer 256->7 as MFMA (w4 staged into Bs) ------
    {
        const int id  = tid;                  // 0..511
        const int ktq = id >> 4, nn4 = id & 15;
        #pragma unroll
        for (int e = 0; e < 8; e++)
            Bs[id*8 + e] = f2h_s((nn4 < NC_) ?
                w4[(size_t)(ktq*8 + e)*NC_ + nn4] : 0.f);
    }
    __syncthreads();

    f32x4 facc[2] = {(f32x4){0.f,0.f,0.f,0.f}, (f32x4){0.f,0.f,0.f,0.f}};
    #pragma unroll
    for (int kt = 0; kt < 8; kt++){
        f16x8 bfr = *(const f16x8*)&Bs[((kt*4 + quad)*16 + n16)*8];
        #pragma unroll
        for (int mt = 0; mt < 2; mt++){
            const int frow = wave*32 + mt*16 + n16;
            const int phys = (kt*4 + quad) ^ (frow & 7);
            f16x8 af = *(const f16x8*)&hbuf[frow*256 + phys*8];
            facc[mt] = __builtin_amdgcn_mfma_f32_16x16x32_f16(af, bfr, facc[mt], 0, 0, 0);
        }
    }
    if (n16 < NC_){
        const float bv = b4[n16];
        #pragma unroll
        for (int mt = 0; mt < 2; mt++){
            #pragma unroll
            for (int r = 0; r < 4; r++){
                const int grow = m0 + wave*32 + mt*16 + quad*4 + r;
                const int bidx = grow >> 12, hw = grow & 4095;
                out[(size_t)(bidx*NC_ + n16)*HW_ + hw] = facc[mt][r] + bv;
            }
        }
    }
}

// ---------------------------------------------------------------------------
// Workspace (peak 159,383,552 B, proven):
//   yseq fp16 [50][256][4096] @ 0 (104,857,600)         ODE w, DFT r
//   fbuf fp16 [65536][416] @ 104,857,600 (54,525,952)   DFT w, MLP r
//     conv temps (10 x 4 MiB) aliased in fbuf region (dead before DFT)
//   wt1/2/3 fp16 @ 0 (yseq region, dead after DFT)
// ---------------------------------------------------------------------------
extern "C" void kernel_launch(void* const* d_in, const int* in_sizes, int n_in,
                              void* d_out, int out_size, void* d_ws, size_t ws_size,
                              hipStream_t stream)
{
    const float* x     = (const float*)d_in[0];
    const float* om_w1 = (const float*)d_in[1];  const float* om_b1 = (const float*)d_in[2];
    const float* om_w2 = (const float*)d_in[3];  const float* om_b2 = (const float*)d_in[4];
    const float* om_w3 = (const float*)d_in[5];  const float* om_b3 = (const float*)d_in[6];
    const float* al_w1 = (const float*)d_in[7];  const float* al_b1 = (const float*)d_in[8];
    const float* al_w2 = (const float*)d_in[9];  const float* al_b2 = (const float*)d_in[10];
    const float* al_w3 = (const float*)d_in[11]; const float* al_b3 = (const float*)d_in[12];
    const float* hy_w1 = (const float*)d_in[13]; const float* hy_b1 = (const float*)d_in[14];
    const float* hy_w2 = (const float*)d_in[15]; const float* hy_b2 = (const float*)d_in[16];
    const float* hy_w3 = (const float*)d_in[17]; const float* hy_b3 = (const float*)d_in[18];
    const float* hy_w4 = (const float*)d_in[19]; const float* hy_b4 = (const float*)d_in[20];
    const float* wy    = (const float*)d_in[21];
    const float* ro_w1 = (const float*)d_in[22]; const float* ro_b1 = (const float*)d_in[23];
    const float* ro_w2 = (const float*)d_in[24]; const float* ro_b2 = (const float*)d_in[25];
    const float* ro_w3 = (const float*)d_in[26]; const float* ro_b3 = (const float*)d_in[27];
    const float* ro_w4 = (const float*)d_in[28]; const float* ro_b4 = (const float*)d_in[29];
    float* out = (float*)d_out;

    char* wsb = (char*)d_ws;
    const size_t YSEQ_BYTES = (size_t)T_ * BCHW_ * 2;          // 104,857,600
    __half* yseq = (__half*)wsb;
    __half* fbuf = (__half*)(wsb + YSEQ_BYTES);

    const size_t MB4 = (size_t)BCHW_ * 4;                      // 4 MiB
    float* om_t1 = (float*)(wsb + YSEQ_BYTES + 0*MB4);
    float* al_t1 = (float*)(wsb + YSEQ_BYTES + 1*MB4);
    float* hy_t1 = (float*)(wsb + YSEQ_BYTES + 2*MB4);
    float* om_t2 = (float*)(wsb + YSEQ_BYTES + 3*MB4);
    float* al_t2 = (float*)(wsb + YSEQ_BYTES + 4*MB4);
    float* hy_t2 = (float*)(wsb + YSEQ_BYTES + 5*MB4);
    float* om_t3 = (float*)(wsb + YSEQ_BYTES + 6*MB4);
    float* alpha = (float*)(wsb + YSEQ_BYTES + 7*MB4);
    float* hy_t3 = (float*)(wsb + YSEQ_BYTES + 8*MB4);
    float* hy0   = (float*)(wsb + YSEQ_BYTES + 9*MB4);
    float* omega = om_t3;

    __half* wt1 = (__half*)(wsb + 0);          // 212,992 B
    __half* wt2 = (__half*)(wsb + 212992);     // 131,072 B
    __half* wt3 = (__half*)(wsb + 344064);     // 131,072 B

    // encoders: 3 chains fused per layer, 8-row slices, 2 px/thread packed
    convf_kernel<1,0><<<dim3(8,B_,3), 256, 0, stream>>>(
        x, x, x, om_w1, al_w1, hy_w1, om_b1, al_b1, hy_b1, om_t1, al_t1, hy_t1);
    convf_kernel<16,0><<<dim3(8,B_,3), 256, 0, stream>>>(
        om_t1, al_t1, hy_t1, om_w2, al_w2, hy_w2, om_b2, al_b2, hy_b2, om_t2, al_t2, hy_t2);
    convf_kernel<16,0><<<dim3(8,B_,3), 256, 0, stream>>>(
        om_t2, al_t2, hy_t2, om_w3, al_w3, hy_w3, om_b3, al_b3, hy_b3, omega, alpha, hy_t3);
    convf_kernel<16,1><<<dim3(8,B_,1), 256, 0, stream>>>(
        hy_t3, hy_t3, hy_t3, hy_w4, hy_w4, hy_w4, hy_b4, hy_b4, hy_b4, hy0, hy0, hy0);
    // 50-step ODE (packed f32x2 math, fp16 yseq out)
    ode_kernel<<<256, 1024, 0, stream>>>(omega, alpha, hy0, wy, yseq);
    // MFMA DFT: rfft magnitude -> row-major fp16 features
    dft_mfma_kernel<<<4096, 256, 0, stream>>>(yseq, fbuf);
    // merged weight transposes (yseq dead; wt at workspace base)
    prep_all_kernel<<<768, 256, 0, stream>>>(ro_w1, ro_w2, ro_w3, wt1, wt2, wt3);
    // fused readout MLP (TILE_M=256; L1 BK=32, L2/3 BK=64)
    mlp_fused_kernel<<<256, 512, 0, stream>>>(
        fbuf, wt1, wt2, wt3, ro_b1, ro_b2, ro_b3, ro_w4, ro_b4, out);
}

// Round 16
// 371.426 us; speedup vs baseline: 1.1382x; 1.1382x over previous
//
#include <hip/hip_runtime.h>
#include <hip/hip_bf16.h>
#include <hip/hip_fp16.h>
#include <math.h>

#define B_   16
#define C_   16
#define S_   64
#define HW_  4096
#define T_   50
#define K_   26
#define F_   416   // C_*K_
#define HID_ 256
#define NC_  7
#define DT_  0.5f
#define BCHW_ (B_*C_*HW_)
#define M_   (B_*HW_)   // 65536 rows into the MLP

typedef _Float16 f16x8  __attribute__((ext_vector_type(8)));
typedef __fp16   fp16x2 __attribute__((ext_vector_type(2)));
typedef float    f32x4  __attribute__((ext_vector_type(4)));
typedef float    f32x2  __attribute__((ext_vector_type(2)));

__device__ __forceinline__ void gld_lds16(const void* g, void* l){
    __builtin_amdgcn_global_load_lds(
        (const __attribute__((address_space(1))) void*)g,
        (__attribute__((address_space(3))) void*)l, 16, 0, 0);
}

__device__ __forceinline__ float fast_tanh(float x){
    float ax = fabsf(x);
    float e  = __expf(2.f*ax);
    float r  = 1.f - 2.f/(e + 1.f);
    return copysignf(r, x);
}

__device__ __forceinline__ short f2h_s(float f){
    __half h = __float2half(f);
    return *(short*)&h;
}

// ---------------------------------------------------------------------------
// Fused multi-chain 3x3 conv, zero 'SAME' padding, PACKED: each thread
// computes 2 x-adjacent pixels for all 16 output channels via f32x2.
// 256 threads, 8-row slices. Block = (slice, batch, chain).
// ---------------------------------------------------------------------------
template<int CIN, int ACT>
__global__ __launch_bounds__(256) void convf_kernel(
    const float* __restrict__ in0, const float* __restrict__ in1, const float* __restrict__ in2,
    const float* __restrict__ w0,  const float* __restrict__ w1,  const float* __restrict__ w2,
    const float* __restrict__ b0,  const float* __restrict__ b1,  const float* __restrict__ b2,
    float* __restrict__ o0, float* __restrict__ o1, float* __restrict__ o2)
{
    __shared__ __align__(16) float slab[CIN][10][66];
    const int slice = blockIdx.x;        // 0..7 -> rows 8*slice..8*slice+7
    const int b     = blockIdx.y;
    const int ch    = blockIdx.z;
    const float* in = (ch == 0) ? in0 : (ch == 1) ? in1 : in2;
    const float* w  = (ch == 0) ? w0  : (ch == 1) ? w1  : w2;
    const float* bb = (ch == 0) ? b0  : (ch == 1) ? b1  : b2;
    float* out      = (ch == 0) ? o0  : (ch == 1) ? o1  : o2;

    const int tid = threadIdx.x;
    const int y0  = slice * 8;

    for (int idx = tid; idx < CIN*10*66; idx += 256){
        int ci  = idx / (10*66);
        int rem = idx % (10*66);
        int rr  = rem / 66;
        int cc  = rem % 66;
        int gy = y0 - 1 + rr;
        int gx = cc - 1;
        float v = 0.f;
        if ((unsigned)gy < 64u && (unsigned)gx < 64u)
            v = in[(size_t)(b*CIN + ci)*HW_ + gy*64 + gx];
        slab[ci][rr][cc] = v;
    }
    __syncthreads();

    const int x2 = (tid & 31) * 2;       // 0,2,...,62 (owns px x2, x2+1)
    const int ry = tid >> 5;             // 0..7

    f32x2 acc[16];
    #pragma unroll
    for (int co = 0; co < 16; co++) acc[co] = (f32x2){bb[co], bb[co]};

    for (int ci = 0; ci < CIN; ci++){
        f32x2 p[3][3];
        #pragma unroll
        for (int dy = 0; dy < 3; dy++){
            float s0 = slab[ci][ry + dy][x2 + 0];
            float s1 = slab[ci][ry + dy][x2 + 1];
            float s2 = slab[ci][ry + dy][x2 + 2];
            float s3 = slab[ci][ry + dy][x2 + 3];
            p[dy][0] = (f32x2){s0, s1};
            p[dy][1] = (f32x2){s1, s2};
            p[dy][2] = (f32x2){s2, s3};
        }
        #pragma unroll
        for (int co = 0; co < 16; co++){
            const float* wp = w + (size_t)(co*CIN + ci)*9;
            f32x2 s = acc[co];
            #pragma unroll
            for (int dy = 0; dy < 3; dy++)
                #pragma unroll
                for (int dx = 0; dx < 3; dx++){
                    float wc = wp[dy*3 + dx];
                    s += (f32x2){wc, wc} * p[dy][dx];
                }
            acc[co] = s;
        }
    }
    #pragma unroll
    for (int co = 0; co < 16; co++){
        float v0 = acc[co].x, v1 = acc[co].y;
        if (ACT){ v0 = fast_tanh(v0); v1 = fast_tanh(v1); }
        else    { v0 = fmaxf(v0, 0.f); v1 = fmaxf(v1, 0.f); }
        *(float2*)&out[(size_t)(b*16 + co)*HW_ + (y0 + ry)*64 + x2] =
            make_float2(v0, v1);
    }
}

// ---------------------------------------------------------------------------
// 50-step coRNN ODE, row-segment ownership (4 x-consecutive px/thread).
// Stencil + state updates in packed f32x2; tanh scalar. LDS row stride 68.
// One packed 8B global store/step.
// ---------------------------------------------------------------------------
__global__ __launch_bounds__(1024) void ode_kernel(
    const float* __restrict__ omega, const float* __restrict__ alpha,
    const float* __restrict__ hy0,   const float* __restrict__ wy,
    __half* __restrict__ yseq)
{
    __shared__ __align__(16) float buf[2][64*68];
    const int blk = blockIdx.x;            // b*16 + c
    const int c   = blk & 15;
    const int tid = threadIdx.x;
    const int y   = tid >> 4;
    const int xq  = (tid & 15) << 2;
    const size_t off = (size_t)blk * HW_;
    const int g0  = y*64 + xq;

    float4 om4 = *(const float4*)(omega + off + g0);
    float4 al4 = *(const float4*)(alpha + off + g0);
    float4 h4  = *(const float4*)(hy0   + off + g0);

    f32x2 om2[2] = { (f32x2){DT_*om4.x, DT_*om4.y}, (f32x2){DT_*om4.z, DT_*om4.w} };
    f32x2 al2[2] = { (f32x2){1.f - DT_*al4.x, 1.f - DT_*al4.y},
                     (f32x2){1.f - DT_*al4.z, 1.f - DT_*al4.w} };
    f32x2 hz2[2] = { (f32x2){0.f, 0.f}, (f32x2){0.f, 0.f} };
    float hv[4]  = { h4.x, h4.y, h4.z, h4.w };
    *(float4*)&buf[0][y*68 + xq] = h4;

    float wv[9];
    const float* wp = wy + (size_t)(c*C_ + c)*9;
    #pragma unroll
    for (int j = 0; j < 9; j++) wv[j] = wp[j];
    const bool five = (wv[0]==0.f) & (wv[2]==0.f) & (wv[6]==0.f) & (wv[8]==0.f);
    const f32x2 w1v = (f32x2){wv[1], wv[1]};
    const f32x2 w3v = (f32x2){wv[3], wv[3]};
    const f32x2 w4v = (f32x2){wv[4], wv[4]};
    const f32x2 w5v = (f32x2){wv[5], wv[5]};
    const f32x2 w7v = (f32x2){wv[7], wv[7]};
    const f32x2 dt2 = (f32x2){DT_, DT_};
    __syncthreads();

    const int ym = ((y + 63) & 63) * 68;
    const int yp = ((y + 1)  & 63) * 68;
    const int yo = y * 68;
    const int xm = (xq + 63) & 63;
    const int xp = (xq + 4)  & 63;
    const __half* ybase = yseq + off + g0;

    int cur = 0;
    for (int t = 0; t < T_; t++){
        const float* hp = buf[cur];
        float* hn = buf[cur ^ 1];
        float4 up4 = *(const float4*)&hp[ym + xq];
        float4 dn4 = *(const float4*)&hp[yp + xq];
        float lft = hp[yo + xm];
        float rgt = hp[yo + xp];

        float ny0, ny1, ny2, ny3;
        if (five){
            f32x2 u0 = (f32x2){up4.x, up4.y}, u1 = (f32x2){up4.z, up4.w};
            f32x2 d0 = (f32x2){dn4.x, dn4.y}, d1 = (f32x2){dn4.z, dn4.w};
            f32x2 c0 = (f32x2){hv[0], hv[1]}, c1 = (f32x2){hv[2], hv[3]};
            f32x2 l0 = (f32x2){lft,  hv[0]};
            f32x2 l1 = (f32x2){hv[1], hv[2]};
            f32x2 r1 = (f32x2){hv[3], rgt};

            f32x2 s0 = w4v*c0 + w1v*u0 + w7v*d0 + w3v*l0 + w5v*l1;
            f32x2 s1 = w4v*c1 + w1v*u1 + w7v*d1 + w3v*l1 + w5v*r1;

            f32x2 sf0 = (f32x2){fast_tanh(s0.x), fast_tanh(s0.y)};
            f32x2 sf1 = (f32x2){fast_tanh(s1.x), fast_tanh(s1.y)};

            f32x2 nz0 = al2[0]*hz2[0] - om2[0]*c0 + dt2*sf0;
            f32x2 nz1 = al2[1]*hz2[1] - om2[1]*c1 + dt2*sf1;
            f32x2 nyv0 = dt2*nz0 + c0;
            f32x2 nyv1 = dt2*nz1 + c1;
            hz2[0] = nz0; hz2[1] = nz1;
            ny0 = nyv0.x; ny1 = nyv0.y; ny2 = nyv1.x; ny3 = nyv1.y;
        } else {
            float upv[4] = {up4.x, up4.y, up4.z, up4.w};
            float dnv[4] = {dn4.x, dn4.y, dn4.z, dn4.w};
            float ul = hp[ym + xm], ur = hp[ym + xp];
            float dl = hp[yp + xm], dr = hp[yp + xp];
            float hzl[4] = {hz2[0].x, hz2[0].y, hz2[1].x, hz2[1].y};
            float oml[4] = {om2[0].x, om2[0].y, om2[1].x, om2[1].y};
            float all[4] = {al2[0].x, al2[0].y, al2[1].x, al2[1].y};
            float nyv[4];
            #pragma unroll
            for (int i = 0; i < 4; i++){
                float l  = (i == 0) ? lft : hv[i-1];
                float r  = (i == 3) ? rgt : hv[i+1];
                float uL = (i == 0) ? ul  : upv[i-1];
                float uR = (i == 3) ? ur  : upv[i+1];
                float dL = (i == 0) ? dl  : dnv[i-1];
                float dR = (i == 3) ? dr  : dnv[i+1];
                float s = wv[0]*uL + wv[1]*upv[i] + wv[2]*uR
                        + wv[3]*l  + wv[4]*hv[i]  + wv[5]*r
                        + wv[6]*dL + wv[7]*dnv[i] + wv[8]*dR;
                float sf = fast_tanh(s);
                float nz = fmaf(all[i], hzl[i], fmaf(-oml[i], hv[i], DT_*sf));
                nyv[i] = fmaf(DT_, nz, hv[i]);
                hzl[i] = nz;
            }
            hz2[0] = (f32x2){hzl[0], hzl[1]};
            hz2[1] = (f32x2){hzl[2], hzl[3]};
            ny0 = nyv[0]; ny1 = nyv[1]; ny2 = nyv[2]; ny3 = nyv[3];
        }

        hv[0] = ny0; hv[1] = ny1; hv[2] = ny2; hv[3] = ny3;
        *(float4*)&hn[yo + xq] = make_float4(ny0, ny1, ny2, ny3);

        union { fp16x2 h2[2]; uint2 u; } pk;
        pk.h2[0] = __builtin_amdgcn_cvt_pkrtz(ny0, ny1);
        pk.h2[1] = __builtin_amdgcn_cvt_pkrtz(ny2, ny3);
        *(uint2*)(ybase + (size_t)t*BCHW_) = pk.u;

        __syncthreads();
        cur ^= 1;
    }
}

// ---------------------------------------------------------------------------
// MFMA DFT. fp16 in/out.
// ---------------------------------------------------------------------------
__global__ __launch_bounds__(256) void dft_mfma_kernel(
    const __half* __restrict__ yseq, __half* __restrict__ f)
{
    __shared__ __align__(16) char Ys[8*256*16];
    __shared__ __align__(16) char Gs[8*64*16];
    const int tid = threadIdx.x;
    const int blk = blockIdx.x;
    const int bc  = blk >> 4;
    const int p0  = (blk & 15) << 8;
    const int b   = bc >> 4, c = bc & 15;

    for (int idx = tid; idx < 64*64; idx += 256){
        int r = idx >> 6, t = idx & 63;
        float v = 0.f;
        if (r < 52 && t < 50){
            int k  = r >> 1;
            int ph = (k * t) % 50;
            float ang = (float)ph * (6.2831853071795864f / 50.f);
            v = (r & 1) ? __sinf(ang) : __cosf(ang);
        }
        *(_Float16*)(Gs + ((t >> 3)*64 + r)*16 + (t & 7)*2) = (_Float16)v;
    }

    {
        const __half* src = yseq + (size_t)bc*HW_ + p0 + tid;
        #pragma unroll
        for (int t2 = 0; t2 < 25; t2++){
            unsigned int a = *(const unsigned short*)&src[(size_t)(2*t2)*BCHW_];
            unsigned int d = *(const unsigned short*)&src[(size_t)(2*t2+1)*BCHW_];
            int t8 = t2 >> 2, j = t2 & 3;
            *(unsigned int*)(Ys + (t8*256 + tid)*16 + j*4) = a | (d << 16);
        }
        #pragma unroll
        for (int t2 = 25; t2 < 32; t2++){
            int t8 = t2 >> 2, j = t2 & 3;
            *(unsigned int*)(Ys + (t8*256 + tid)*16 + j*4) = 0u;
        }
    }
    __syncthreads();

    const int lane = tid & 63;
    const int w    = tid >> 6;
    const int n    = lane & 15;
    const int quad = lane >> 4;
    const int mrow = 16*w + n;

    f16x8 a0 = *(const f16x8*)(Gs + ((quad    )*64 + mrow)*16);
    f16x8 a1 = *(const f16x8*)(Gs + ((quad + 4)*64 + mrow)*16);

    const int kb0   = 8*w + 2*quad;
    const bool valid = (kb0 < K_);

    for (int nt = 0; nt < 16; nt++){
        f16x8 b0 = *(const f16x8*)(Ys + ((quad    )*256 + nt*16 + n)*16);
        f16x8 b1 = *(const f16x8*)(Ys + ((quad + 4)*256 + nt*16 + n)*16);
        f32x4 acc = (f32x4){0.f, 0.f, 0.f, 0.f};
        acc = __builtin_amdgcn_mfma_f32_16x16x32_f16(a0, b0, acc, 0, 0, 0);
        acc = __builtin_amdgcn_mfma_f32_16x16x32_f16(a1, b1, acc, 0, 0, 0);
        if (valid){
            float m0 = sqrtf(fmaf(acc[0], acc[0], acc[1]*acc[1]));
            float m1 = sqrtf(fmaf(acc[2], acc[2], acc[3]*acc[3]));
            unsigned int u = ((unsigned int)(unsigned short)f2h_s(m1) << 16)
                           |  (unsigned int)(unsigned short)f2h_s(m0);
            const int row = b*HW_ + p0 + nt*16 + n;
            *(unsigned int*)((char*)(f + (size_t)row*F_ + c*K_) + kb0*2) = u;
        }
    }
}

// ---------------------------------------------------------------------------
// One merged prep kernel: wt1 [256][416], wt2/wt3 [256][256], all fp16.
// ---------------------------------------------------------------------------
__global__ __launch_bounds__(256) void prep_all_kernel(
    const float* __restrict__ w1, const float* __restrict__ w2,
    const float* __restrict__ w3,
    __half* __restrict__ wt1, __half* __restrict__ wt2, __half* __restrict__ wt3)
{
    const int blk = blockIdx.x;
    const int tid = threadIdx.x;
    if (blk < 256){
        const int n = blk;
        for (int k = tid; k < F_; k += 256)
            wt1[(size_t)n*F_ + k] = __float2half(w1[(size_t)k*HID_ + n]);
    } else if (blk < 512){
        const int n = blk - 256;
        for (int k = tid; k < HID_; k += 256)
            wt2[(size_t)n*HID_ + k] = __float2half(w2[(size_t)k*HID_ + n]);
    } else {
        const int n = blk - 512;
        for (int k = tid; k < HID_; k += 256)
            wt3[(size_t)n*HID_ + k] = __float2half(w3[(size_t)k*HID_ + n]);
    }
}

// ---------------------------------------------------------------------------
// FUSED MLP (round-12 proven: TILE_M=256, 8 waves, BK=32, padded Bs,
// hbuf stride 264, separate Bs4; 61.4 us, zero spill).
// ---------------------------------------------------------------------------
__global__ __launch_bounds__(512, 2) void mlp_fused_kernel(
    const __half* __restrict__ A,     // fbuf [M][416]
    const __half* __restrict__ Wt1,   // [256][416]
    const __half* __restrict__ Wt2,   // [256][256]
    const __half* __restrict__ Wt3,   // [256][256]
    const float* __restrict__ b1, const float* __restrict__ b2,
    const float* __restrict__ b3,
    const float* __restrict__ w4, const float* __restrict__ b4,
    float* __restrict__ out)
{
    __shared__ __align__(16) short hbuf[256*264];   // 135,168 B
    __shared__ __align__(16) short Bs[4*2064];      //  16,512 B (4128 B/section)
    __shared__ __align__(16) short Bs4[512*8];      //   8,192 B (w4 fragments)

    const int tid  = threadIdx.x;
    const int lane = tid & 63;
    const int wave = tid >> 6;
    const int wm   = (wave & 3) * 64;
    const int wn   = (wave >> 2) * 128;
    const int n16  = lane & 15;
    const int quad = lane >> 4;
    const int m0   = blockIdx.x * 256;

    {
        const int ktq = tid >> 4, n = tid & 15;
        short vals[8];
        #pragma unroll
        for (int e = 0; e < 8; e++){
            const int k = ktq*8 + e;
            vals[e] = f2h_s((n < NC_) ? w4[(size_t)k*NC_ + n] : 0.f);
        }
        #pragma unroll
        for (int e = 0; e < 8; e++) Bs4[tid*8 + e] = vals[e];
    }

    const int id0 = tid, id1 = tid + 512;
    const int kc0 = id0 >> 8, nn0 = id0 & 255;
    const int kc1 = id1 >> 8, nn1 = id1 & 255;
    char* dst0 = (char*)Bs + kc0*4128 + nn0*16;
    char* dst1 = (char*)Bs + kc1*4128 + nn1*16;

    f32x4 acc[4][8];
    #pragma unroll
    for (int i = 0; i < 4; i++)
        #pragma unroll
        for (int j = 0; j < 8; j++)
            acc[i][j] = (f32x4){0.f,0.f,0.f,0.f};

    // ---------------- layer 1: A from global ----------------
    const __half* arow[4];
    #pragma unroll
    for (int i = 0; i < 4; i++)
        arow[i] = A + (size_t)(m0 + wm + i*16 + n16)*F_ + quad*8;

    f16x8 afn[4];
    #pragma unroll
    for (int i = 0; i < 4; i++) afn[i] = *(const f16x8*)(arow[i]);

    for (int k0 = 0; k0 < F_; k0 += 32){
        gld_lds16(Wt1 + (size_t)nn0*F_ + k0 + kc0*8, dst0);
        gld_lds16(Wt1 + (size_t)nn1*F_ + k0 + kc1*8, dst1);
        __syncthreads();
        f16x8 af[4];
        #pragma unroll
        for (int i = 0; i < 4; i++) af[i] = afn[i];
        if (k0 + 32 < F_){
            #pragma unroll
            for (int i = 0; i < 4; i++) afn[i] = *(const f16x8*)(arow[i] + k0 + 32);
        }
        f16x8 bf[8];
        #pragma unroll
        for (int j = 0; j < 8; j++)
            bf[j] = *(const f16x8*)((char*)Bs + quad*4128 + (wn + j*16 + n16)*16);
        #pragma unroll
        for (int i = 0; i < 4; i++)
            #pragma unroll
            for (int j = 0; j < 8; j++)
                acc[i][j] = __builtin_amdgcn_mfma_f32_16x16x32_f16(
                                af[i], bf[j], acc[i][j], 0, 0, 0);
        __syncthreads();
    }
    #pragma unroll
    for (int j = 0; j < 8; j++){
        const int col = wn + j*16 + n16;
        const float bv = b1[col];
        #pragma unroll
        for (int i = 0; i < 4; i++){
            const int r0 = wm + i*16 + quad*4;
            #pragma unroll
            for (int r = 0; r < 4; r++)
                hbuf[(r0 + r)*264 + col] = f2h_s(fmaxf(acc[i][j][r] + bv, 0.f));
        }
    }
    __syncthreads();

    // ---------------- layers 2,3: A from hbuf ----------------
    const __half* Wts[2] = {Wt2, Wt3};
    const float* bls[2] = {b2, b3};
    for (int L = 0; L < 2; L++){
        const __half* Wt = Wts[L];
        #pragma unroll
        for (int i = 0; i < 4; i++)
            #pragma unroll
            for (int j = 0; j < 8; j++)
                acc[i][j] = (f32x4){0.f,0.f,0.f,0.f};

        for (int k0 = 0; k0 < HID_; k0 += 32){
            gld_lds16(Wt + (size_t)nn0*HID_ + k0 + kc0*8, dst0);
            gld_lds16(Wt + (size_t)nn1*HID_ + k0 + kc1*8, dst1);
            f16x8 af[4];
            #pragma unroll
            for (int i = 0; i < 4; i++)
                af[i] = *(const f16x8*)&hbuf[(wm + i*16 + n16)*264 + k0 + quad*8];
            __syncthreads();
            f16x8 bf[8];
            #pragma unroll
            for (int j = 0; j < 8; j++)
                bf[j] = *(const f16x8*)((char*)Bs + quad*4128 + (wn + j*16 + n16)*16);
            #pragma unroll
            for (int i = 0; i < 4; i++)
                #pragma unroll
                for (int j = 0; j < 8; j++)
                    acc[i][j] = __builtin_amdgcn_mfma_f32_16x16x32_f16(
                                    af[i], bf[j], acc[i][j], 0, 0, 0);
            __syncthreads();
        }
        const float* bl = bls[L];
        #pragma unroll
        for (int j = 0; j < 8; j++){
            const int col = wn + j*16 + n16;
            const float bv = bl[col];
            #pragma unroll
            for (int i = 0; i < 4; i++){
                const int r0 = wm + i*16 + quad*4;
                #pragma unroll
                for (int r = 0; r < 4; r++)
                    hbuf[(r0 + r)*264 + col] = f2h_s(fmaxf(acc[i][j][r] + bv, 0.f));
            }
        }
        __syncthreads();
    }

    // ---------------- final layer 256 -> 7 as MFMA + NCHW transpose --------
    f32x4 facc[2] = {(f32x4){0.f,0.f,0.f,0.f}, (f32x4){0.f,0.f,0.f,0.f}};
    #pragma unroll
    for (int kt = 0; kt < 8; kt++){
        f16x8 bfr = *(const f16x8*)&Bs4[((kt*4 + quad)*16 + n16)*8];
        #pragma unroll
        for (int mt = 0; mt < 2; mt++){
            f16x8 af = *(const f16x8*)&hbuf[(wave*32 + mt*16 + n16)*264 + kt*32 + quad*8];
            facc[mt] = __builtin_amdgcn_mfma_f32_16x16x32_f16(af, bfr, facc[mt], 0, 0, 0);
        }
    }
    if (n16 < NC_){
        const float bv = b4[n16];
        #pragma unroll
        for (int mt = 0; mt < 2; mt++){
            #pragma unroll
            for (int r = 0; r < 4; r++){
                const int grow = m0 + wave*32 + mt*16 + quad*4 + r;
                const int bidx = grow >> 12, hw = grow & 4095;
                out[(size_t)(bidx*NC_ + n16)*HW_ + hw] = facc[mt][r] + bv;
            }
        }
    }
}

// ---------------------------------------------------------------------------
// Workspace (peak 159,383,552 B, proven):
//   yseq fp16 [50][256][4096] @ 0 (104,857,600)         ODE w, DFT r
//   fbuf fp16 [65536][416] @ 104,857,600 (54,525,952)   DFT w, MLP r
//     conv temps (10 x 4 MiB) aliased in fbuf region (dead before DFT)
//   wt1/2/3 fp16 @ 0 (yseq region, dead after DFT)
// ---------------------------------------------------------------------------
extern "C" void kernel_launch(void* const* d_in, const int* in_sizes, int n_in,
                              void* d_out, int out_size, void* d_ws, size_t ws_size,
                              hipStream_t stream)
{
    const float* x     = (const float*)d_in[0];
    const float* om_w1 = (const float*)d_in[1];  const float* om_b1 = (const float*)d_in[2];
    const float* om_w2 = (const float*)d_in[3];  const float* om_b2 = (const float*)d_in[4];
    const float* om_w3 = (const float*)d_in[5];  const float* om_b3 = (const float*)d_in[6];
    const float* al_w1 = (const float*)d_in[7];  const float* al_b1 = (const float*)d_in[8];
    const float* al_w2 = (const float*)d_in[9];  const float* al_b2 = (const float*)d_in[10];
    const float* al_w3 = (const float*)d_in[11]; const float* al_b3 = (const float*)d_in[12];
    const float* hy_w1 = (const float*)d_in[13]; const float* hy_b1 = (const float*)d_in[14];
    const float* hy_w2 = (const float*)d_in[15]; const float* hy_b2 = (const float*)d_in[16];
    const float* hy_w3 = (const float*)d_in[17]; const float* hy_b3 = (const float*)d_in[18];
    const float* hy_w4 = (const float*)d_in[19]; const float* hy_b4 = (const float*)d_in[20];
    const float* wy    = (const float*)d_in[21];
    const float* ro_w1 = (const float*)d_in[22]; const float* ro_b1 = (const float*)d_in[23];
    const float* ro_w2 = (const float*)d_in[24]; const float* ro_b2 = (const float*)d_in[25];
    const float* ro_w3 = (const float*)d_in[26]; const float* ro_b3 = (const float*)d_in[27];
    const float* ro_w4 = (const float*)d_in[28]; const float* ro_b4 = (const float*)d_in[29];
    float* out = (float*)d_out;

    char* wsb = (char*)d_ws;
    const size_t YSEQ_BYTES = (size_t)T_ * BCHW_ * 2;          // 104,857,600
    __half* yseq = (__half*)wsb;
    __half* fbuf = (__half*)(wsb + YSEQ_BYTES);

    const size_t MB4 = (size_t)BCHW_ * 4;                      // 4 MiB
    float* om_t1 = (float*)(wsb + YSEQ_BYTES + 0*MB4);
    float* al_t1 = (float*)(wsb + YSEQ_BYTES + 1*MB4);
    float* hy_t1 = (float*)(wsb + YSEQ_BYTES + 2*MB4);
    float* om_t2 = (float*)(wsb + YSEQ_BYTES + 3*MB4);
    float* al_t2 = (float*)(wsb + YSEQ_BYTES + 4*MB4);
    float* hy_t2 = (float*)(wsb + YSEQ_BYTES + 5*MB4);
    float* omega = (float*)(wsb + YSEQ_BYTES + 6*MB4);
    float* alpha = (float*)(wsb + YSEQ_BYTES + 7*MB4);
    float* hy_t3 = (float*)(wsb + YSEQ_BYTES + 8*MB4);
    float* hy0   = (float*)(wsb + YSEQ_BYTES + 9*MB4);

    __half* wt1 = (__half*)(wsb + 0);          // 212,992 B
    __half* wt2 = (__half*)(wsb + 212992);     // 131,072 B
    __half* wt3 = (__half*)(wsb + 344064);     // 131,072 B

    // encoders: 3 chains fused per layer, 8-row slices, 2 px/thread packed
    convf_kernel<1,0><<<dim3(8,B_,3), 256, 0, stream>>>(
        x, x, x, om_w1, al_w1, hy_w1, om_b1, al_b1, hy_b1, om_t1, al_t1, hy_t1);
    convf_kernel<16,0><<<dim3(8,B_,3), 256, 0, stream>>>(
        om_t1, al_t1, hy_t1, om_w2, al_w2, hy_w2, om_b2, al_b2, hy_b2, om_t2, al_t2, hy_t2);
    convf_kernel<16,0><<<dim3(8,B_,3), 256, 0, stream>>>(
        om_t2, al_t2, hy_t2, om_w3, al_w3, hy_w3, om_b3, al_b3, hy_b3, omega, alpha, hy_t3);
    convf_kernel<16,1><<<dim3(8,B_,1), 256, 0, stream>>>(
        hy_t3, hy_t3, hy_t3, hy_w4, hy_w4, hy_w4, hy_b4, hy_b4, hy_b4, hy0, hy0, hy0);
    // 50-step ODE (packed f32x2 math, fp16 yseq out)
    ode_kernel<<<256, 1024, 0, stream>>>(omega, alpha, hy0, wy, yseq);
    // MFMA DFT: rfft magnitude -> row-major fp16 features
    dft_mfma_kernel<<<4096, 256, 0, stream>>>(yseq, fbuf);
    // merged weight transposes (yseq dead; wt at workspace base)
    prep_all_kernel<<<768, 256, 0, stream>>>(ro_w1, ro_w2, ro_w3, wt1, wt2, wt3);
    // fused readout MLP (3 GEMMs + MFMA final layer + transpose)
    mlp_fused_kernel<<<256, 512, 0, stream>>>(
        fbuf, wt1, wt2, wt3, ro_b1, ro_b2, ro_b3, ro_w4, ro_b4, out);
}